// Round 1
// baseline (1724.347 us; speedup 1.0000x reference)
//
#include <hip/hip_runtime.h>
#include <math.h>

#define N_NODES 131072
#define N_EDGES 262144
#define N_B     4096
// NODE_DIM=16, EDGE_DIM=4, HIDDEN=64, MLP_HID=128

#define TE 96   // edges per block in k_edge

__device__ __forceinline__ float fast_sig(float x) {
    return 1.0f / (1.0f + __expf(-x));
}
__device__ __forceinline__ float fast_tanh(float x) {
    float t = __expf(-2.0f * fabsf(x));
    float r = (1.0f - t) / (1.0f + t);
    return copysignf(r, x);
}

// -------- starts[g] = lower_bound(batch, g); starts[B] = N --------
__global__ void k_starts(const int* __restrict__ batch, int* __restrict__ starts) {
    int g = blockIdx.x * blockDim.x + threadIdx.x;
    if (g > N_B) return;
    if (g == N_B) { starts[N_B] = N_NODES; return; }
    int lo = 0, hi = N_NODES;
    while (lo < hi) {
        int mid = (lo + hi) >> 1;
        if (batch[mid] < g) lo = mid + 1; else hi = mid;
    }
    starts[g] = lo;
}

// -------- fused edge MLP + message + atomic scatter --------
// msg[e,h] = sum_d x[src,d] * (sum_k h1[e,k]*w2[k, d*64+h] + b2[d*64+h])
__global__ __launch_bounds__(256, 2) void k_edge(
    const float* __restrict__ x,     // [N,16]
    const float* __restrict__ ea,    // [E,4]
    const int*   __restrict__ eidx,  // [2,E]
    const float* __restrict__ we1,   // [4,128]
    const float* __restrict__ be1,   // [128]
    const float* __restrict__ we2,   // [128,1024]
    const float* __restrict__ be2,   // [1024]
    float* __restrict__ msum,        // [N,64]
    float* __restrict__ cnt)         // [N]
{
    __shared__ float h1s[TE][132];   // +4 pad: conflict-free b128 reads
    __shared__ float xs[TE][16];
    __shared__ float eas[TE][4];
    __shared__ int   dsts[TE];
    const int tid = threadIdx.x;
    const int eb  = blockIdx.x * TE;

    // ---- stage edge_attr, dst, x[src] ----
    for (int v = tid; v < TE * 4; v += 256) {
        int e = v >> 2, j = v & 3;
        eas[e][j] = (eb + e < N_EDGES) ? ea[(size_t)(eb + e) * 4 + j] : 0.0f;
    }
    if (tid < TE) {
        int idx = eb + tid;
        dsts[tid] = (idx < N_EDGES) ? eidx[N_EDGES + idx] : 0;
    }
    for (int v = tid; v < TE * 16; v += 256) {
        int e = v >> 4, d = v & 15;
        int idx = eb + e;
        int s = (idx < N_EDGES) ? eidx[idx] : 0;
        xs[e][d] = x[(size_t)s * 16 + d];
    }
    __syncthreads();

    // ---- h1 = relu(ea @ we1 + be1) ----
    for (int v = tid; v < TE * 128; v += 256) {
        int e = v >> 7, k = v & 127;
        float acc = be1[k]
                  + eas[e][0] * we1[k]
                  + eas[e][1] * we1[128 + k]
                  + eas[e][2] * we1[256 + k]
                  + eas[e][3] * we1[384 + k];
        h1s[e][k] = fmaxf(acc, 0.0f);
    }
    __syncthreads();

    // ---- GEMM + d-contraction ----
    const int hg = tid & 15;   // h0 = hg*4
    const int eg = tid >> 4;   // edges eg + 16*i, i<6
    const int h0 = hg * 4;

    float msg[6][4];
    #pragma unroll
    for (int i = 0; i < 6; ++i)
        #pragma unroll
        for (int j = 0; j < 4; ++j) msg[i][j] = 0.0f;

    #pragma unroll 1
    for (int d = 0; d < 16; ++d) {
        float s4[6][4];
        #pragma unroll
        for (int i = 0; i < 6; ++i)
            #pragma unroll
            for (int j = 0; j < 4; ++j) s4[i][j] = 0.0f;

        const float* wp = we2 + d * 64 + h0;
        #pragma unroll 2
        for (int k = 0; k < 128; k += 4) {
            float4 w0 = *(const float4*)(wp + (size_t)(k + 0) * 1024);
            float4 w1 = *(const float4*)(wp + (size_t)(k + 1) * 1024);
            float4 w2 = *(const float4*)(wp + (size_t)(k + 2) * 1024);
            float4 w3 = *(const float4*)(wp + (size_t)(k + 3) * 1024);
            #pragma unroll
            for (int i = 0; i < 6; ++i) {
                float4 a = *(const float4*)(&h1s[eg + 16 * i][k]);
                s4[i][0] += a.x * w0.x + a.y * w1.x + a.z * w2.x + a.w * w3.x;
                s4[i][1] += a.x * w0.y + a.y * w1.y + a.z * w2.y + a.w * w3.y;
                s4[i][2] += a.x * w0.z + a.y * w1.z + a.z * w2.z + a.w * w3.z;
                s4[i][3] += a.x * w0.w + a.y * w1.w + a.z * w2.w + a.w * w3.w;
            }
        }
        float4 bv = *(const float4*)(be2 + d * 64 + h0);
        #pragma unroll
        for (int i = 0; i < 6; ++i) {
            float xv = xs[eg + 16 * i][d];
            msg[i][0] += xv * (s4[i][0] + bv.x);
            msg[i][1] += xv * (s4[i][1] + bv.y);
            msg[i][2] += xv * (s4[i][2] + bv.z);
            msg[i][3] += xv * (s4[i][3] + bv.w);
        }
    }

    // ---- scatter ----
    #pragma unroll
    for (int i = 0; i < 6; ++i) {
        int el = eg + 16 * i;
        if (eb + el < N_EDGES) {
            float* p = msum + (size_t)dsts[el] * 64 + h0;
            atomicAdd(p + 0, msg[i][0]);
            atomicAdd(p + 1, msg[i][1]);
            atomicAdd(p + 2, msg[i][2]);
            atomicAdd(p + 3, msg[i][3]);
        }
    }
    if (hg == 0) {
        #pragma unroll
        for (int i = 0; i < 6; ++i) {
            int el = eg + 16 * i;
            if (eb + el < N_EDGES) atomicAdd(&cnt[dsts[el]], 1.0f);
        }
    }
}

// -------- out = relu(msum/max(cnt,1) + x@root + conv_bias), in place --------
__global__ __launch_bounds__(256) void k_combine(
    float* __restrict__ buf, const float* __restrict__ cnt,
    const float* __restrict__ x, const float* __restrict__ root,
    const float* __restrict__ cb)
{
    int gid = blockIdx.x * 256 + threadIdx.x;
    int n = gid >> 6, h = gid & 63;
    float c = cnt[n];
    float agg = buf[gid] / fmaxf(c, 1.0f);
    float acc = cb[h];
    #pragma unroll
    for (int d = 0; d < 16; ++d)
        acc += x[(size_t)n * 16 + d] * root[d * 64 + h];
    buf[gid] = fmaxf(agg + acc, 0.0f);
}

// -------- 3-step GRU, per-node, in place --------
// out==h every step => r,z gates use summed weights (wih+whh rows 0..127)
__global__ __launch_bounds__(256) void k_gru(
    float* __restrict__ buf,          // [N,64] in-out
    const float* __restrict__ wih,    // [192,64]
    const float* __restrict__ whh,    // [192,64]
    const float* __restrict__ bih,    // [192]
    const float* __restrict__ bhh)    // [192]
{
    __shared__ float Wrz[128][64];    // wih+whh, rows 0..127
    __shared__ float Wn[64][128];     // [j][k]=wih[128+j][k], [j][64+k]=whh[128+j][k]
    const int tid = threadIdx.x;

    for (int v = tid; v < 128 * 64; v += 256)
        Wrz[v >> 6][v & 63] = wih[v] + whh[v];
    for (int v = tid; v < 64 * 128; v += 256) {
        int j = v >> 7, k = v & 127;
        Wn[j][k] = (k < 64) ? wih[(128 + j) * 64 + k] : whh[(128 + j) * 64 + (k - 64)];
    }
    __syncthreads();

    size_t n = (size_t)blockIdx.x * 256 + tid;
    float* row = buf + n * 64;
    float h[64];
    #pragma unroll
    for (int k = 0; k < 64; k += 4) {
        float4 t = *(const float4*)(row + k);
        h[k] = t.x; h[k + 1] = t.y; h[k + 2] = t.z; h[k + 3] = t.w;
    }

    #pragma unroll 1
    for (int step = 0; step < 3; ++step) {
        #pragma unroll 1
        for (int j = 0; j < 64; ++j) {
            float ra = bih[j] + bhh[j];
            float za = bih[64 + j] + bhh[64 + j];
            float ia = bih[128 + j];
            float ha = bhh[128 + j];
            #pragma unroll
            for (int k = 0; k < 64; k += 4) {
                float4 wr = *(const float4*)&Wrz[j][k];
                float4 wz = *(const float4*)&Wrz[64 + j][k];
                float4 wi = *(const float4*)&Wn[j][k];
                float4 wh = *(const float4*)&Wn[j][64 + k];
                ra += h[k] * wr.x + h[k + 1] * wr.y + h[k + 2] * wr.z + h[k + 3] * wr.w;
                za += h[k] * wz.x + h[k + 1] * wz.y + h[k + 2] * wz.z + h[k + 3] * wz.w;
                ia += h[k] * wi.x + h[k + 1] * wi.y + h[k + 2] * wi.z + h[k + 3] * wi.w;
                ha += h[k] * wh.x + h[k + 1] * wh.y + h[k + 2] * wh.z + h[k + 3] * wh.w;
            }
            float r = fast_sig(ra);
            float z = fast_sig(za);
            float nv = fast_tanh(ia + r * ha);
            row[j] = (1.0f - z) * nv + z * row[j];  // row[j] still holds old h[j]
        }
        if (step < 2) {
            #pragma unroll
            for (int k = 0; k < 64; k += 4) {
                float4 t = *(const float4*)(row + k);
                h[k] = t.x; h[k + 1] = t.y; h[k + 2] = t.z; h[k + 3] = t.w;
            }
        }
    }
}

// -------- Set2Set (3 steps) + final MLP; 16 graphs per block --------
__global__ __launch_bounds__(256) void k_s2s(
    const float* __restrict__ out,    // [N,64]
    const int*   __restrict__ starts, // [B+1]
    const float* __restrict__ wih,    // [256,128]
    const float* __restrict__ whh,    // [256,64]
    const float* __restrict__ bih,    // [256]
    const float* __restrict__ bhh,    // [256]
    const float* __restrict__ fc1w,   // [128,64]
    const float* __restrict__ fc1b,   // [64]
    const float* __restrict__ fc2w,   // [64]
    const float* __restrict__ fc2b,   // [1]
    float* __restrict__ y)            // [B]
{
    __shared__ float hl[16][64], cl[16][64], qs[16][128];
    __shared__ float gates[16][256];
    __shared__ float ebuf[16][256];
    const int tid = threadIdx.x;
    const int wave = tid >> 6, lane = tid & 63;
    const int g0 = blockIdx.x * 16;

    for (int v = tid; v < 16 * 64; v += 256) { hl[v >> 6][v & 63] = 0.0f; cl[v >> 6][v & 63] = 0.0f; }
    for (int v = tid; v < 16 * 128; v += 256) qs[v >> 7][v & 127] = 0.0f;
    __syncthreads();

    #pragma unroll 1
    for (int step = 0; step < 3; ++step) {
        // LSTM gates: thread = row c, 16 graphs at once
        float acc[16];
        float bsum = bih[tid] + bhh[tid];
        #pragma unroll
        for (int g = 0; g < 16; ++g) acc[g] = bsum;
        for (int k = 0; k < 128; ++k) {
            float w = wih[tid * 128 + k];
            #pragma unroll
            for (int g = 0; g < 16; ++g) acc[g] += w * qs[g][k];
        }
        for (int k = 0; k < 64; ++k) {
            float w = whh[tid * 64 + k];
            #pragma unroll
            for (int g = 0; g < 16; ++g) acc[g] += w * hl[g][k];
        }
        #pragma unroll
        for (int g = 0; g < 16; ++g) gates[g][tid] = acc[g];
        __syncthreads();

        // LSTM state update: 16 g x 64 l
        #pragma unroll
        for (int rr = 0; rr < 4; ++rr) {
            int item = rr * 256 + tid;
            int g = item >> 6, l = item & 63;
            float ig = fast_sig(gates[g][l]);
            float fg = fast_sig(gates[g][64 + l]);
            float gg = fast_tanh(gates[g][128 + l]);
            float og = fast_sig(gates[g][192 + l]);
            float cn = fg * cl[g][l] + ig * gg;
            cl[g][l] = cn;
            float hn = og * fast_tanh(cn);
            hl[g][l] = hn;
            qs[g][l] = hn;     // q part of q_star
        }
        __syncthreads();

        // attention: wave handles 4 graphs
        for (int gi = 0; gi < 4; ++gi) {
            int g = wave * 4 + gi;
            int s = starts[g0 + g], e = starts[g0 + g + 1];
            int L = e - s; if (L > 256) L = 256;   // P(L>256) ~ 0 (mean 32)
            float m = -1e30f;
            for (int c = 0; c * 64 < L; ++c) {
                int j = c * 64 + lane;
                if (j < L) {
                    const float* orow = out + (size_t)(s + j) * 64;
                    float a = 0.0f;
                    #pragma unroll
                    for (int l = 0; l < 64; ++l) a += orow[l] * hl[g][l];
                    ebuf[g][j] = a;
                    m = fmaxf(m, a);
                }
            }
            #pragma unroll
            for (int off = 32; off; off >>= 1) m = fmaxf(m, __shfl_xor(m, off));
            float ds = 0.0f;
            for (int c = 0; c * 64 < L; ++c) {
                int j = c * 64 + lane;
                if (j < L) {
                    float ex = __expf(ebuf[g][j] - m);
                    ebuf[g][j] = ex;
                    ds += ex;
                }
            }
            #pragma unroll
            for (int off = 32; off; off >>= 1) ds += __shfl_xor(ds, off);
            // r_g: lane = h
            float r = 0.0f;
            for (int j = 0; j < L; ++j)
                r += ebuf[g][j] * out[(size_t)(s + j) * 64 + lane];
            r = (L > 0) ? (r / ds) : 0.0f;
            qs[g][64 + lane] = r;
        }
        __syncthreads();
    }

    // final MLP: u = relu(q_star@fc1 + b); y = u@fc2 + b2
    #pragma unroll
    for (int rr = 0; rr < 4; ++rr) {
        int item = rr * 256 + tid;
        int g = item >> 6, l = item & 63;
        float a = fc1b[l];
        for (int k = 0; k < 128; ++k) a += qs[g][k] * fc1w[k * 64 + l];
        ebuf[g][l] = fmaxf(a, 0.0f);
    }
    __syncthreads();
    if (tid < 16) {
        float a = fc2b[0];
        #pragma unroll
        for (int l = 0; l < 64; ++l) a += ebuf[tid][l] * fc2w[l];
        y[g0 + tid] = a;
    }
}

extern "C" void kernel_launch(void* const* d_in, const int* in_sizes, int n_in,
                              void* d_out, int out_size, void* d_ws, size_t ws_size,
                              hipStream_t stream) {
    const float* x     = (const float*)d_in[0];
    const float* ea    = (const float*)d_in[1];
    const int*   eidx  = (const int*)d_in[2];
    const int*   batch = (const int*)d_in[3];
    const float* we1   = (const float*)d_in[4];
    const float* be1   = (const float*)d_in[5];
    const float* we2   = (const float*)d_in[6];
    const float* be2   = (const float*)d_in[7];
    const float* root  = (const float*)d_in[8];
    const float* cb    = (const float*)d_in[9];
    const float* gwih  = (const float*)d_in[10];
    const float* gwhh  = (const float*)d_in[11];
    const float* gbih  = (const float*)d_in[12];
    const float* gbhh  = (const float*)d_in[13];
    const float* lwih  = (const float*)d_in[14];
    const float* lwhh  = (const float*)d_in[15];
    const float* lbih  = (const float*)d_in[16];
    const float* lbhh  = (const float*)d_in[17];
    const float* fc1w  = (const float*)d_in[18];
    const float* fc1b  = (const float*)d_in[19];
    const float* fc2w  = (const float*)d_in[20];
    const float* fc2b  = (const float*)d_in[21];

    float* buf = (float*)d_ws;                      // [N,64] msum -> conv out -> GRU out
    float* cnt = buf + (size_t)N_NODES * 64;        // [N]
    int* starts = (int*)(cnt + N_NODES);            // [B+1]
    float* y = (float*)d_out;

    hipMemsetAsync(d_ws, 0, ((size_t)N_NODES * 64 + N_NODES) * sizeof(float), stream);
    k_starts<<<(N_B + 1 + 255) / 256, 256, 0, stream>>>(batch, starts);
    k_edge<<<(N_EDGES + TE - 1) / TE, 256, 0, stream>>>(x, ea, eidx, we1, be1, we2, be2, buf, cnt);
    k_combine<<<(N_NODES * 64) / 256, 256, 0, stream>>>(buf, cnt, x, root, cb);
    k_gru<<<N_NODES / 256, 256, 0, stream>>>(buf, gwih, gwhh, gbih, gbhh);
    k_s2s<<<N_B / 16, 256, 0, stream>>>(buf, starts, lwih, lwhh, lbih, lbhh,
                                        fc1w, fc1b, fc2w, fc2b, y);
}

// Round 3
// 932.612 us; speedup vs baseline: 1.8489x; 1.8489x over previous
//
#include <hip/hip_runtime.h>
#include <math.h>

#define N_NODES 131072
#define N_EDGES 262144
#define N_B     4096
// NODE_DIM=16, EDGE_DIM=4, HIDDEN=64, MLP_HID=128

typedef __attribute__((ext_vector_type(8))) short short8;
typedef __attribute__((ext_vector_type(4))) float f32x4;

__device__ __forceinline__ float fast_sig(float x) {
    return 1.0f / (1.0f + __expf(-x));
}
__device__ __forceinline__ float fast_tanh(float x) {
    float t = __expf(-2.0f * fabsf(x));
    float r = (1.0f - t) / (1.0f + t);
    return copysignf(r, x);
}

// round-to-nearest-even fp32 -> bf16 (bit trick), plus residual split
__device__ __forceinline__ unsigned short bf16_rne(float v) {
    unsigned u = __float_as_uint(v);
    u += 0x7FFFu + ((u >> 16) & 1u);
    return (unsigned short)(u >> 16);
}
__device__ __forceinline__ void split_bf16(float v, short& hi, short& lo) {
    unsigned short h = bf16_rne(v);
    float hf = __uint_as_float((unsigned)h << 16);
    unsigned short l = bf16_rne(v - hf);
    hi = (short)h; lo = (short)l;
}

// -------- starts[g] = lower_bound(batch, g); starts[B] = N --------
__global__ void k_starts(const int* __restrict__ batch, int* __restrict__ starts) {
    int g = blockIdx.x * blockDim.x + threadIdx.x;
    if (g > N_B) return;
    if (g == N_B) { starts[N_B] = N_NODES; return; }
    int lo = 0, hi = N_NODES;
    while (lo < hi) {
        int mid = (lo + hi) >> 1;
        if (batch[mid] < g) lo = mid + 1; else hi = mid;
    }
    starts[g] = lo;
}

// -------- prep: split we2 into bf16 hi/lo in MFMA B-frag order --------
// wt layout (ushort): [d(16)][hl(2)][u(4)][s(4)][lane(64)][j(8)]
// element = W_d[kk = s*32 + (lane>>4)*8 + j][h = u*16 + (lane&15)]
//         = we2[kk*1024 + d*64 + h]
__global__ __launch_bounds__(256) void k_prep_w(const float* __restrict__ we2,
                                                unsigned short* __restrict__ wt) {
    int p = blockIdx.x * 256 + threadIdx.x;  // [0, 16384)
    int d = p >> 10;
    int u = (p >> 8) & 3;
    int s = (p >> 6) & 3;
    int l = p & 63;
    int kk0 = s * 32 + (l >> 4) * 8;
    int h = u * 16 + (l & 15);
    short8 hv, lv;
    #pragma unroll
    for (int j = 0; j < 8; ++j) {
        float v = we2[(size_t)(kk0 + j) * 1024 + d * 64 + h];
        short hi, lo; split_bf16(v, hi, lo);
        hv[j] = hi; lv[j] = lo;
    }
    size_t base = (size_t)d * 16384 + (size_t)u * 2048 + s * 512 + l * 8;
    *(short8*)&wt[base] = hv;           // hl=0
    *(short8*)&wt[base + 8192] = lv;    // hl=1
}

// -------- fused edge MLP + MFMA message GEMM + atomic scatter --------
// 128 edges/block, 256 threads = 4 waves; wave w owns m-tiles {w, w+4}.
// B fragments read directly from global (wt is L1/L2-resident); A frags in
// registers; NO barriers inside the K/d loop (single __syncthreads total).
__global__ __launch_bounds__(256, 2) void k_edge(
    const float* __restrict__ x,     // [N,16]
    const float* __restrict__ ea,    // [E,4]
    const int*   __restrict__ eidx,  // [2,E]
    const float* __restrict__ we1,   // [4,128]
    const float* __restrict__ be1,   // [128]
    const unsigned short* __restrict__ wt,  // pre-split we2 frags
    const float* __restrict__ be2,   // [1024]
    float* __restrict__ msum,        // [N,64]
    float* __restrict__ cnt)         // [N]
{
    __shared__ unsigned short sAh[16384];  // [t(8)][s(4)][lane(64)][j(8)] 32KB
    __shared__ unsigned short sAl[16384];  // 32KB
    __shared__ float sx[128 * 16];         // 8KB
    __shared__ float sbe2[1024];           // 4KB
    __shared__ int   sdst[128];

    const int tid = threadIdx.x;
    const int w   = tid >> 6;     // wave
    const int ln  = tid & 63;     // lane
    const int lq  = ln >> 4;      // quad
    const int lm  = ln & 15;
    const int eb  = blockIdx.x * 128;

    // ---- stage dst, be2 ----
    if (tid < 128) sdst[tid] = eidx[N_EDGES + eb + tid];
    #pragma unroll
    for (int v = tid; v < 1024; v += 256) sbe2[v] = be2[v];

    // ---- stage x[src] ----
    #pragma unroll
    for (int v = tid; v < 512; v += 256) {
        int e = v >> 2, q = v & 3;
        int src = eidx[eb + e];
        float4 t4 = ((const float4*)(x + (size_t)src * 16))[q];
        ((float4*)sx)[e * 4 + q] = t4;
    }

    // ---- h1 = relu(ea @ we1 + be1), split to bf16 hi/lo, A-frag layout ----
    #pragma unroll 1
    for (int i = 0; i < 8; ++i) {
        int cc = tid + i * 256;         // chunk id [0,2048): [t(8)][s(4)][l(64)]
        int t  = cc >> 8;
        int r8 = cc & 255;
        int s  = r8 >> 6;
        int l  = r8 & 63;
        int e   = t * 16 + (l & 15);
        int kk0 = s * 32 + (l >> 4) * 8;
        float4 eav = *(const float4*)(ea + (size_t)(eb + e) * 4);
        float4 b0 = *(const float4*)(be1 + kk0);
        float4 b1 = *(const float4*)(be1 + kk0 + 4);
        float acc[8] = {b0.x, b0.y, b0.z, b0.w, b1.x, b1.y, b1.z, b1.w};
        #pragma unroll
        for (int a = 0; a < 4; ++a) {
            float4 wa0 = *(const float4*)(we1 + a * 128 + kk0);
            float4 wa1 = *(const float4*)(we1 + a * 128 + kk0 + 4);
            float ev = (a == 0) ? eav.x : (a == 1) ? eav.y : (a == 2) ? eav.z : eav.w;
            acc[0] += ev * wa0.x; acc[1] += ev * wa0.y;
            acc[2] += ev * wa0.z; acc[3] += ev * wa0.w;
            acc[4] += ev * wa1.x; acc[5] += ev * wa1.y;
            acc[6] += ev * wa1.z; acc[7] += ev * wa1.w;
        }
        short8 hv, lv;
        #pragma unroll
        for (int j = 0; j < 8; ++j) {
            float v = fmaxf(acc[j], 0.0f);
            short hi, lo; split_bf16(v, hi, lo);
            hv[j] = hi; lv[j] = lo;
        }
        *(short8*)&sAh[cc * 8] = hv;
        *(short8*)&sAl[cc * 8] = lv;
    }
    __syncthreads();   // the ONLY barrier

    // ---- hoist A fragments to registers (d-invariant) ----
    short8 ah[2][4], al[2][4];
    #pragma unroll
    for (int t2 = 0; t2 < 2; ++t2) {
        int t = w + 4 * t2;
        #pragma unroll
        for (int s = 0; s < 4; ++s) {
            ah[t2][s] = *(short8*)&sAh[((t * 4 + s) * 64 + ln) * 8];
            al[t2][s] = *(short8*)&sAl[((t * 4 + s) * 64 + ln) * 8];
        }
    }

    // ---- main loop over d: B from global (cache-resident), MFMA, x-scale ----
    f32x4 msg[2][4];
    #pragma unroll
    for (int t = 0; t < 2; ++t)
        #pragma unroll
        for (int u = 0; u < 4; ++u) msg[t][u] = (f32x4){0.f, 0.f, 0.f, 0.f};

    #pragma unroll 1
    for (int d = 0; d < 16; ++d) {
        const unsigned short* wd = wt + (size_t)d * 16384;
        f32x4 c2[2][4];
        #pragma unroll
        for (int u = 0; u < 4; ++u) {
            float bv = sbe2[d * 64 + u * 16 + lm];
            c2[0][u] = (f32x4){bv, bv, bv, bv};
            c2[1][u] = (f32x4){bv, bv, bv, bv};
        }
        short8 bh[2][4], bl[2][4];
        #pragma unroll
        for (int u = 0; u < 4; ++u) {
            bh[0][u] = *(const short8*)(wd + u * 2048 + ln * 8);
            bl[0][u] = *(const short8*)(wd + 8192 + u * 2048 + ln * 8);
        }
        #pragma unroll
        for (int s = 0; s < 4; ++s) {
            const int cs = s & 1, ns = cs ^ 1;
            if (s < 3) {
                #pragma unroll
                for (int u = 0; u < 4; ++u) {
                    bh[ns][u] = *(const short8*)(wd + u * 2048 + (s + 1) * 512 + ln * 8);
                    bl[ns][u] = *(const short8*)(wd + 8192 + u * 2048 + (s + 1) * 512 + ln * 8);
                }
            }
            #pragma unroll
            for (int u = 0; u < 4; ++u) {
                c2[0][u] = __builtin_amdgcn_mfma_f32_16x16x32_bf16(ah[0][s], bh[cs][u], c2[0][u], 0, 0, 0);
                c2[1][u] = __builtin_amdgcn_mfma_f32_16x16x32_bf16(ah[1][s], bh[cs][u], c2[1][u], 0, 0, 0);
                c2[0][u] = __builtin_amdgcn_mfma_f32_16x16x32_bf16(ah[0][s], bl[cs][u], c2[0][u], 0, 0, 0);
                c2[1][u] = __builtin_amdgcn_mfma_f32_16x16x32_bf16(ah[1][s], bl[cs][u], c2[1][u], 0, 0, 0);
                c2[0][u] = __builtin_amdgcn_mfma_f32_16x16x32_bf16(al[0][s], bh[cs][u], c2[0][u], 0, 0, 0);
                c2[1][u] = __builtin_amdgcn_mfma_f32_16x16x32_bf16(al[1][s], bh[cs][u], c2[1][u], 0, 0, 0);
            }
        }
        // epilogue: msg += x[:,d] * C_d
        #pragma unroll
        for (int t = 0; t < 2; ++t) {
            #pragma unroll
            for (int r = 0; r < 4; ++r) {
                float xv = sx[((w + 4 * t) * 16 + lq * 4 + r) * 16 + d];
                #pragma unroll
                for (int u = 0; u < 4; ++u)
                    msg[t][u][r] = fmaf(xv, c2[t][u][r], msg[t][u][r]);
            }
        }
    }

    // ---- scatter ----
    #pragma unroll
    for (int t = 0; t < 2; ++t) {
        #pragma unroll
        for (int r = 0; r < 4; ++r) {
            int e_local = (w + 4 * t) * 16 + lq * 4 + r;
            int dst = sdst[e_local];
            float* p = msum + (size_t)dst * 64 + lm;
            #pragma unroll
            for (int u = 0; u < 4; ++u)
                atomicAdd(p + u * 16, msg[t][u][r]);
            if (lm == 0) atomicAdd(&cnt[dst], 1.0f);
        }
    }
}

// -------- out = relu(msum/max(cnt,1) + x@root + conv_bias), in place --------
__global__ __launch_bounds__(256) void k_combine(
    float* __restrict__ buf, const float* __restrict__ cnt,
    const float* __restrict__ x, const float* __restrict__ root,
    const float* __restrict__ cb)
{
    int gid = blockIdx.x * 256 + threadIdx.x;
    int n = gid >> 6, h = gid & 63;
    float c = cnt[n];
    float agg = buf[gid] / fmaxf(c, 1.0f);
    float acc = cb[h];
    #pragma unroll
    for (int d = 0; d < 16; ++d)
        acc += x[(size_t)n * 16 + d] * root[d * 64 + h];
    buf[gid] = fmaxf(agg + acc, 0.0f);
}

// -------- 3-step GRU, per-node, in place --------
__global__ __launch_bounds__(256) void k_gru(
    float* __restrict__ buf,          // [N,64] in-out
    const float* __restrict__ wih,    // [192,64]
    const float* __restrict__ whh,    // [192,64]
    const float* __restrict__ bih,    // [192]
    const float* __restrict__ bhh)    // [192]
{
    __shared__ float Wrz[128][64];
    __shared__ float Wn[64][128];
    const int tid = threadIdx.x;

    for (int v = tid; v < 128 * 64; v += 256)
        Wrz[v >> 6][v & 63] = wih[v] + whh[v];
    for (int v = tid; v < 64 * 128; v += 256) {
        int j = v >> 7, k = v & 127;
        Wn[j][k] = (k < 64) ? wih[(128 + j) * 64 + k] : whh[(128 + j) * 64 + (k - 64)];
    }
    __syncthreads();

    size_t n = (size_t)blockIdx.x * 256 + tid;
    float* row = buf + n * 64;
    float h[64];
    #pragma unroll
    for (int k = 0; k < 64; k += 4) {
        float4 t = *(const float4*)(row + k);
        h[k] = t.x; h[k + 1] = t.y; h[k + 2] = t.z; h[k + 3] = t.w;
    }

    #pragma unroll 1
    for (int step = 0; step < 3; ++step) {
        #pragma unroll 1
        for (int j = 0; j < 64; ++j) {
            float ra = bih[j] + bhh[j];
            float za = bih[64 + j] + bhh[64 + j];
            float ia = bih[128 + j];
            float ha = bhh[128 + j];
            #pragma unroll
            for (int k = 0; k < 64; k += 4) {
                float4 wr = *(const float4*)&Wrz[j][k];
                float4 wz = *(const float4*)&Wrz[64 + j][k];
                float4 wi = *(const float4*)&Wn[j][k];
                float4 wh = *(const float4*)&Wn[j][64 + k];
                ra += h[k] * wr.x + h[k + 1] * wr.y + h[k + 2] * wr.z + h[k + 3] * wr.w;
                za += h[k] * wz.x + h[k + 1] * wz.y + h[k + 2] * wz.z + h[k + 3] * wz.w;
                ia += h[k] * wi.x + h[k + 1] * wi.y + h[k + 2] * wi.z + h[k + 3] * wi.w;
                ha += h[k] * wh.x + h[k + 1] * wh.y + h[k + 2] * wh.z + h[k + 3] * wh.w;
            }
            float r = fast_sig(ra);
            float z = fast_sig(za);
            float nv = fast_tanh(ia + r * ha);
            row[j] = (1.0f - z) * nv + z * row[j];
        }
        if (step < 2) {
            #pragma unroll
            for (int k = 0; k < 64; k += 4) {
                float4 t = *(const float4*)(row + k);
                h[k] = t.x; h[k + 1] = t.y; h[k + 2] = t.z; h[k + 3] = t.w;
            }
        }
    }
}

// -------- Set2Set (3 steps) + final MLP; 16 graphs per block --------
__global__ __launch_bounds__(256) void k_s2s(
    const float* __restrict__ out,    // [N,64]
    const int*   __restrict__ starts, // [B+1]
    const float* __restrict__ wih,    // [256,128]
    const float* __restrict__ whh,    // [256,64]
    const float* __restrict__ bih,    // [256]
    const float* __restrict__ bhh,    // [256]
    const float* __restrict__ fc1w,   // [128,64]
    const float* __restrict__ fc1b,   // [64]
    const float* __restrict__ fc2w,   // [64]
    const float* __restrict__ fc2b,   // [1]
    float* __restrict__ y)            // [B]
{
    __shared__ float hl[16][64], cl[16][64], qs[16][128];
    __shared__ float gates[16][256];
    __shared__ float ebuf[16][256];
    const int tid = threadIdx.x;
    const int wave = tid >> 6, lane = tid & 63;
    const int g0 = blockIdx.x * 16;

    for (int v = tid; v < 16 * 64; v += 256) { hl[v >> 6][v & 63] = 0.0f; cl[v >> 6][v & 63] = 0.0f; }
    for (int v = tid; v < 16 * 128; v += 256) qs[v >> 7][v & 127] = 0.0f;
    __syncthreads();

    #pragma unroll 1
    for (int step = 0; step < 3; ++step) {
        float acc[16];
        float bsum = bih[tid] + bhh[tid];
        #pragma unroll
        for (int g = 0; g < 16; ++g) acc[g] = bsum;
        for (int k = 0; k < 128; ++k) {
            float w = wih[tid * 128 + k];
            #pragma unroll
            for (int g = 0; g < 16; ++g) acc[g] += w * qs[g][k];
        }
        for (int k = 0; k < 64; ++k) {
            float w = whh[tid * 64 + k];
            #pragma unroll
            for (int g = 0; g < 16; ++g) acc[g] += w * hl[g][k];
        }
        #pragma unroll
        for (int g = 0; g < 16; ++g) gates[g][tid] = acc[g];
        __syncthreads();

        #pragma unroll
        for (int rr = 0; rr < 4; ++rr) {
            int item = rr * 256 + tid;
            int g = item >> 6, l = item & 63;
            float ig = fast_sig(gates[g][l]);
            float fg = fast_sig(gates[g][64 + l]);
            float gg = fast_tanh(gates[g][128 + l]);
            float og = fast_sig(gates[g][192 + l]);
            float cn = fg * cl[g][l] + ig * gg;
            cl[g][l] = cn;
            float hn = og * fast_tanh(cn);
            hl[g][l] = hn;
            qs[g][l] = hn;
        }
        __syncthreads();

        for (int gi = 0; gi < 4; ++gi) {
            int g = wave * 4 + gi;
            int s = starts[g0 + g], e = starts[g0 + g + 1];
            int L = e - s; if (L > 256) L = 256;
            float m = -1e30f;
            for (int c = 0; c * 64 < L; ++c) {
                int j = c * 64 + lane;
                if (j < L) {
                    const float* orow = out + (size_t)(s + j) * 64;
                    float a = 0.0f;
                    #pragma unroll
                    for (int l = 0; l < 64; ++l) a += orow[l] * hl[g][l];
                    ebuf[g][j] = a;
                    m = fmaxf(m, a);
                }
            }
            #pragma unroll
            for (int off = 32; off; off >>= 1) m = fmaxf(m, __shfl_xor(m, off));
            float ds = 0.0f;
            for (int c = 0; c * 64 < L; ++c) {
                int j = c * 64 + lane;
                if (j < L) {
                    float ex = __expf(ebuf[g][j] - m);
                    ebuf[g][j] = ex;
                    ds += ex;
                }
            }
            #pragma unroll
            for (int off = 32; off; off >>= 1) ds += __shfl_xor(ds, off);
            float r = 0.0f;
            for (int j = 0; j < L; ++j)
                r += ebuf[g][j] * out[(size_t)(s + j) * 64 + lane];
            r = (L > 0) ? (r / ds) : 0.0f;
            qs[g][64 + lane] = r;
        }
        __syncthreads();
    }

    #pragma unroll
    for (int rr = 0; rr < 4; ++rr) {
        int item = rr * 256 + tid;
        int g = item >> 6, l = item & 63;
        float a = fc1b[l];
        for (int k = 0; k < 128; ++k) a += qs[g][k] * fc1w[k * 64 + l];
        ebuf[g][l] = fmaxf(a, 0.0f);
    }
    __syncthreads();
    if (tid < 16) {
        float a = fc2b[0];
        #pragma unroll
        for (int l = 0; l < 64; ++l) a += ebuf[tid][l] * fc2w[l];
        y[g0 + tid] = a;
    }
}

extern "C" void kernel_launch(void* const* d_in, const int* in_sizes, int n_in,
                              void* d_out, int out_size, void* d_ws, size_t ws_size,
                              hipStream_t stream) {
    const float* x     = (const float*)d_in[0];
    const float* ea    = (const float*)d_in[1];
    const int*   eidx  = (const int*)d_in[2];
    const int*   batch = (const int*)d_in[3];
    const float* we1   = (const float*)d_in[4];
    const float* be1   = (const float*)d_in[5];
    const float* we2   = (const float*)d_in[6];
    const float* be2   = (const float*)d_in[7];
    const float* root  = (const float*)d_in[8];
    const float* cb    = (const float*)d_in[9];
    const float* gwih  = (const float*)d_in[10];
    const float* gwhh  = (const float*)d_in[11];
    const float* gbih  = (const float*)d_in[12];
    const float* gbhh  = (const float*)d_in[13];
    const float* lwih  = (const float*)d_in[14];
    const float* lwhh  = (const float*)d_in[15];
    const float* lbih  = (const float*)d_in[16];
    const float* lbhh  = (const float*)d_in[17];
    const float* fc1w  = (const float*)d_in[18];
    const float* fc1b  = (const float*)d_in[19];
    const float* fc2w  = (const float*)d_in[20];
    const float* fc2b  = (const float*)d_in[21];

    float* buf = (float*)d_ws;                      // [N,64]
    float* cnt = buf + (size_t)N_NODES * 64;        // [N]
    int* starts = (int*)(cnt + N_NODES);            // [B+1]
    size_t off = ((size_t)N_NODES * 64 + N_NODES + N_B + 1) * 4;
    off = (off + 15) & ~(size_t)15;
    unsigned short* wt = (unsigned short*)((char*)d_ws + off);  // 512KB frag-split we2
    float* y = (float*)d_out;

    hipMemsetAsync(d_ws, 0, ((size_t)N_NODES * 64 + N_NODES) * sizeof(float), stream);
    k_prep_w<<<64, 256, 0, stream>>>(we2, wt);
    k_starts<<<(N_B + 1 + 255) / 256, 256, 0, stream>>>(batch, starts);
    k_edge<<<N_EDGES / 128, 256, 0, stream>>>(x, ea, eidx, we1, be1, wt, be2, buf, cnt);
    k_combine<<<(N_NODES * 64) / 256, 256, 0, stream>>>(buf, cnt, x, root, cb);
    k_gru<<<N_NODES / 256, 256, 0, stream>>>(buf, gwih, gwhh, gbih, gbhh);
    k_s2s<<<N_B / 16, 256, 0, stream>>>(buf, starts, lwih, lwhh, lbih, lbhh,
                                        fc1w, fc1b, fc2w, fc2b, y);
}

// Round 4
// 547.285 us; speedup vs baseline: 3.1507x; 1.7041x over previous
//
#include <hip/hip_runtime.h>
#include <math.h>

#define N_NODES 131072
#define N_EDGES 262144
#define N_B     4096
// NODE_DIM=16, EDGE_DIM=4, HIDDEN=64, MLP_HID=128

typedef __attribute__((ext_vector_type(8))) short short8;
typedef __attribute__((ext_vector_type(4))) float f32x4;

__device__ __forceinline__ float fast_sig(float x) {
    return 1.0f / (1.0f + __expf(-x));
}
__device__ __forceinline__ float fast_tanh(float x) {
    float t = __expf(-2.0f * fabsf(x));
    float r = (1.0f - t) / (1.0f + t);
    return copysignf(r, x);
}

// round-to-nearest-even fp32 -> bf16 (bit trick), plus residual split
__device__ __forceinline__ unsigned short bf16_rne(float v) {
    unsigned u = __float_as_uint(v);
    u += 0x7FFFu + ((u >> 16) & 1u);
    return (unsigned short)(u >> 16);
}
__device__ __forceinline__ void split_bf16(float v, short& hi, short& lo) {
    unsigned short h = bf16_rne(v);
    float hf = __uint_as_float((unsigned)h << 16);
    unsigned short l = bf16_rne(v - hf);
    hi = (short)h; lo = (short)l;
}

// -------- starts[g] = lower_bound(batch, g); starts[B] = N --------
__global__ void k_starts(const int* __restrict__ batch, int* __restrict__ starts) {
    int g = blockIdx.x * blockDim.x + threadIdx.x;
    if (g > N_B) return;
    if (g == N_B) { starts[N_B] = N_NODES; return; }
    int lo = 0, hi = N_NODES;
    while (lo < hi) {
        int mid = (lo + hi) >> 1;
        if (batch[mid] < g) lo = mid + 1; else hi = mid;
    }
    starts[g] = lo;
}

// -------- prep: split we2 into bf16 hi/lo in MFMA B-frag order --------
// wt layout (ushort): [d(16)][hl(2)][u(4)][s(4)][lane(64)][j(8)]
__global__ __launch_bounds__(256) void k_prep_w(const float* __restrict__ we2,
                                                unsigned short* __restrict__ wt) {
    int p = blockIdx.x * 256 + threadIdx.x;  // [0, 16384)
    int d = p >> 10;
    int u = (p >> 8) & 3;
    int s = (p >> 6) & 3;
    int l = p & 63;
    int kk0 = s * 32 + (l >> 4) * 8;
    int h = u * 16 + (l & 15);
    short8 hv, lv;
    #pragma unroll
    for (int j = 0; j < 8; ++j) {
        float v = we2[(size_t)(kk0 + j) * 1024 + d * 64 + h];
        short hi, lo; split_bf16(v, hi, lo);
        hv[j] = hi; lv[j] = lo;
    }
    size_t base = (size_t)d * 16384 + (size_t)u * 2048 + s * 512 + l * 8;
    *(short8*)&wt[base] = hv;           // hl=0
    *(short8*)&wt[base + 8192] = lv;    // hl=1
}

// -------- prep: GRU weights into B-frag order (split bf16) + summed biases --
// wtg layout (ushort): [u(16)][ks(2)][hl(2)][lane(64)][j(8)]  (64 KB)
// gate col n = u*16 + (lane&15): n<64: r (wih+whh rows 0..63 summed),
// 64..127: z (rows 64..127 summed), 128..191: inn (wih rows 128..191),
// 192..255: hn (whh rows 128..191).  k = ks*32 + (lane>>4)*8 + j.
__global__ __launch_bounds__(256) void k_prep_gru(
    const float* __restrict__ gwih, const float* __restrict__ gwhh,
    const float* __restrict__ gbih, const float* __restrict__ gbhh,
    unsigned short* __restrict__ wtg, float* __restrict__ gbias)
{
    int p = blockIdx.x * 256 + threadIdx.x;  // [0, 2048)
    if (p < 256) {
        int g = p >> 6, j = p & 63;
        float b;
        if (g == 0)      b = gbih[j] + gbhh[j];
        else if (g == 1) b = gbih[64 + j] + gbhh[64 + j];
        else if (g == 2) b = gbih[128 + j];
        else             b = gbhh[128 + j];
        gbias[p] = b;
    }
    int u = p >> 7, ks = (p >> 6) & 1, ln = p & 63;
    int n = u * 16 + (ln & 15);
    int g = n >> 6, jn = n & 63;
    int k0 = ks * 32 + (ln >> 4) * 8;
    short8 hv, lv;
    #pragma unroll
    for (int jj = 0; jj < 8; ++jj) {
        int k = k0 + jj;
        float v;
        if (g == 0)      v = gwih[jn * 64 + k] + gwhh[jn * 64 + k];
        else if (g == 1) v = gwih[(64 + jn) * 64 + k] + gwhh[(64 + jn) * 64 + k];
        else if (g == 2) v = gwih[(128 + jn) * 64 + k];
        else             v = gwhh[(128 + jn) * 64 + k];
        short hi, lo; split_bf16(v, hi, lo);
        hv[jj] = hi; lv[jj] = lo;
    }
    size_t base = (size_t)(u * 2 + ks) * 1024 + ln * 8;  // hl=0
    *(short8*)&wtg[base] = hv;
    *(short8*)&wtg[base + 512] = lv;                     // hl=1
}

// -------- fused edge MLP + MFMA message GEMM + atomic scatter --------
__global__ __launch_bounds__(256, 2) void k_edge(
    const float* __restrict__ x,     // [N,16]
    const float* __restrict__ ea,    // [E,4]
    const int*   __restrict__ eidx,  // [2,E]
    const float* __restrict__ we1,   // [4,128]
    const float* __restrict__ be1,   // [128]
    const unsigned short* __restrict__ wt,  // pre-split we2 frags
    const float* __restrict__ be2,   // [1024]
    float* __restrict__ msum,        // [N,64]
    float* __restrict__ cnt)         // [N]
{
    __shared__ unsigned short sAh[16384];  // [t(8)][s(4)][lane(64)][j(8)] 32KB
    __shared__ unsigned short sAl[16384];  // 32KB
    __shared__ float sx[128 * 16];         // 8KB
    __shared__ float sbe2[1024];           // 4KB
    __shared__ int   sdst[128];

    const int tid = threadIdx.x;
    const int w   = tid >> 6;     // wave
    const int ln  = tid & 63;     // lane
    const int lq  = ln >> 4;      // quad
    const int lm  = ln & 15;
    const int eb  = blockIdx.x * 128;

    if (tid < 128) sdst[tid] = eidx[N_EDGES + eb + tid];
    #pragma unroll
    for (int v = tid; v < 1024; v += 256) sbe2[v] = be2[v];

    #pragma unroll
    for (int v = tid; v < 512; v += 256) {
        int e = v >> 2, q = v & 3;
        int src = eidx[eb + e];
        float4 t4 = ((const float4*)(x + (size_t)src * 16))[q];
        ((float4*)sx)[e * 4 + q] = t4;
    }

    // ---- h1 = relu(ea @ we1 + be1), split to bf16 hi/lo, A-frag layout ----
    #pragma unroll 1
    for (int i = 0; i < 8; ++i) {
        int cc = tid + i * 256;
        int t  = cc >> 8;
        int r8 = cc & 255;
        int s  = r8 >> 6;
        int l  = r8 & 63;
        int e   = t * 16 + (l & 15);
        int kk0 = s * 32 + (l >> 4) * 8;
        float4 eav = *(const float4*)(ea + (size_t)(eb + e) * 4);
        float4 b0 = *(const float4*)(be1 + kk0);
        float4 b1 = *(const float4*)(be1 + kk0 + 4);
        float acc[8] = {b0.x, b0.y, b0.z, b0.w, b1.x, b1.y, b1.z, b1.w};
        #pragma unroll
        for (int a = 0; a < 4; ++a) {
            float4 wa0 = *(const float4*)(we1 + a * 128 + kk0);
            float4 wa1 = *(const float4*)(we1 + a * 128 + kk0 + 4);
            float ev = (a == 0) ? eav.x : (a == 1) ? eav.y : (a == 2) ? eav.z : eav.w;
            acc[0] += ev * wa0.x; acc[1] += ev * wa0.y;
            acc[2] += ev * wa0.z; acc[3] += ev * wa0.w;
            acc[4] += ev * wa1.x; acc[5] += ev * wa1.y;
            acc[6] += ev * wa1.z; acc[7] += ev * wa1.w;
        }
        short8 hv, lv;
        #pragma unroll
        for (int j = 0; j < 8; ++j) {
            float v = fmaxf(acc[j], 0.0f);
            short hi, lo; split_bf16(v, hi, lo);
            hv[j] = hi; lv[j] = lo;
        }
        *(short8*)&sAh[cc * 8] = hv;
        *(short8*)&sAl[cc * 8] = lv;
    }
    __syncthreads();

    short8 ah[2][4], al[2][4];
    #pragma unroll
    for (int t2 = 0; t2 < 2; ++t2) {
        int t = w + 4 * t2;
        #pragma unroll
        for (int s = 0; s < 4; ++s) {
            ah[t2][s] = *(short8*)&sAh[((t * 4 + s) * 64 + ln) * 8];
            al[t2][s] = *(short8*)&sAl[((t * 4 + s) * 64 + ln) * 8];
        }
    }

    f32x4 msg[2][4];
    #pragma unroll
    for (int t = 0; t < 2; ++t)
        #pragma unroll
        for (int u = 0; u < 4; ++u) msg[t][u] = (f32x4){0.f, 0.f, 0.f, 0.f};

    #pragma unroll 1
    for (int d = 0; d < 16; ++d) {
        const unsigned short* wd = wt + (size_t)d * 16384;
        f32x4 c2[2][4];
        #pragma unroll
        for (int u = 0; u < 4; ++u) {
            float bv = sbe2[d * 64 + u * 16 + lm];
            c2[0][u] = (f32x4){bv, bv, bv, bv};
            c2[1][u] = (f32x4){bv, bv, bv, bv};
        }
        short8 bh[2][4], bl[2][4];
        #pragma unroll
        for (int u = 0; u < 4; ++u) {
            bh[0][u] = *(const short8*)(wd + u * 2048 + ln * 8);
            bl[0][u] = *(const short8*)(wd + 8192 + u * 2048 + ln * 8);
        }
        #pragma unroll
        for (int s = 0; s < 4; ++s) {
            const int cs = s & 1, ns = cs ^ 1;
            if (s < 3) {
                #pragma unroll
                for (int u = 0; u < 4; ++u) {
                    bh[ns][u] = *(const short8*)(wd + u * 2048 + (s + 1) * 512 + ln * 8);
                    bl[ns][u] = *(const short8*)(wd + 8192 + u * 2048 + (s + 1) * 512 + ln * 8);
                }
            }
            #pragma unroll
            for (int u = 0; u < 4; ++u) {
                c2[0][u] = __builtin_amdgcn_mfma_f32_16x16x32_bf16(ah[0][s], bh[cs][u], c2[0][u], 0, 0, 0);
                c2[1][u] = __builtin_amdgcn_mfma_f32_16x16x32_bf16(ah[1][s], bh[cs][u], c2[1][u], 0, 0, 0);
                c2[0][u] = __builtin_amdgcn_mfma_f32_16x16x32_bf16(ah[0][s], bl[cs][u], c2[0][u], 0, 0, 0);
                c2[1][u] = __builtin_amdgcn_mfma_f32_16x16x32_bf16(ah[1][s], bl[cs][u], c2[1][u], 0, 0, 0);
                c2[0][u] = __builtin_amdgcn_mfma_f32_16x16x32_bf16(al[0][s], bh[cs][u], c2[0][u], 0, 0, 0);
                c2[1][u] = __builtin_amdgcn_mfma_f32_16x16x32_bf16(al[1][s], bh[cs][u], c2[1][u], 0, 0, 0);
            }
        }
        #pragma unroll
        for (int t = 0; t < 2; ++t) {
            #pragma unroll
            for (int r = 0; r < 4; ++r) {
                float xv = sx[((w + 4 * t) * 16 + lq * 4 + r) * 16 + d];
                #pragma unroll
                for (int u = 0; u < 4; ++u)
                    msg[t][u][r] = fmaf(xv, c2[t][u][r], msg[t][u][r]);
            }
        }
    }

    #pragma unroll
    for (int t = 0; t < 2; ++t) {
        #pragma unroll
        for (int r = 0; r < 4; ++r) {
            int e_local = (w + 4 * t) * 16 + lq * 4 + r;
            int dst = sdst[e_local];
            float* p = msum + (size_t)dst * 64 + lm;
            #pragma unroll
            for (int u = 0; u < 4; ++u)
                atomicAdd(p + u * 16, msg[t][u][r]);
            if (lm == 0) atomicAdd(&cnt[dst], 1.0f);
        }
    }
}

// -------- fused combine + 3-step GRU via in-block MFMA GEMM --------
// 256 nodes/block. gates[256 nodes x 256 cols] = H @ W~^T per step.
// A-frags (h, split bf16) in LDS; B-frags from global wtg (L1-resident);
// old-h carried in C-layout registers after step 0.
__global__ __launch_bounds__(256, 2) void k_gru2(
    float* __restrict__ buf,        // [N,64] in: msum; out: final h
    const float* __restrict__ cnt,  // [N]
    const float* __restrict__ x,    // [N,16]
    const float* __restrict__ root, // [16,64]
    const float* __restrict__ cb,   // [64]
    const unsigned short* __restrict__ wtg,  // [16][2][2][64][8] ushort
    const float* __restrict__ gbias)         // [256]
{
    __shared__ unsigned short sAh[16384];  // [mt(16)][ks(2)][lane(64)][j(8)] 32KB
    __shared__ unsigned short sAl[16384];  // 32KB
    __shared__ float sroot[1024];
    __shared__ float sbias[256];
    __shared__ float scb[64];
    const int tid = threadIdx.x;
    const int w = tid >> 6, ln = tid & 63, lq = ln >> 4, lm = ln & 15;
    const size_t nbase = (size_t)blockIdx.x * 256;

    #pragma unroll
    for (int v = tid; v < 1024; v += 256) sroot[v] = root[v];
    sbias[tid] = gbias[tid];
    if (tid < 64) scb[tid] = cb[tid];
    __syncthreads();

    // ---- initial A build: combine (msum/cnt + x@root + cb, relu) fused ----
    #pragma unroll 1
    for (int i = 0; i < 8; ++i) {
        int cc = tid + i * 256;            // [mt(16)][ks(2)][l(64)]
        int mt = cc >> 7, ks = (cc >> 6) & 1, l = cc & 63;
        size_t gn = nbase + mt * 16 + (l & 15);
        int c0 = ks * 32 + (l >> 4) * 8;
        float4 m0 = *(const float4*)(buf + gn * 64 + c0);
        float4 m1 = *(const float4*)(buf + gn * 64 + c0 + 4);
        float cinv = 1.0f / fmaxf(cnt[gn], 1.0f);
        float xv[16];
        *(float4*)&xv[0]  = *(const float4*)(x + gn * 16);
        *(float4*)&xv[4]  = *(const float4*)(x + gn * 16 + 4);
        *(float4*)&xv[8]  = *(const float4*)(x + gn * 16 + 8);
        *(float4*)&xv[12] = *(const float4*)(x + gn * 16 + 12);
        float acc[8];
        #pragma unroll
        for (int j = 0; j < 8; ++j) acc[j] = scb[c0 + j];
        #pragma unroll
        for (int d = 0; d < 16; ++d) {
            float xd = xv[d];
            #pragma unroll
            for (int j = 0; j < 8; ++j) acc[j] += xd * sroot[d * 64 + c0 + j];
        }
        float ms[8] = {m0.x, m0.y, m0.z, m0.w, m1.x, m1.y, m1.z, m1.w};
        short8 hv, lv;
        #pragma unroll
        for (int j = 0; j < 8; ++j) {
            float hval = fmaxf(ms[j] * cinv + acc[j], 0.0f);
            short hi, lo; split_bf16(hval, hi, lo);
            hv[j] = hi; lv[j] = lo;
        }
        *(short8*)&sAh[cc * 8] = hv;
        *(short8*)&sAl[cc * 8] = lv;
    }
    __syncthreads();

    float hreg[4][4][4];  // [v][i][reg] old h in C-layout, carried across steps
    #pragma unroll 1
    for (int step = 0; step < 3; ++step) {
        // A-frag loads (wave w owns m-tiles 4w..4w+3)
        short8 ah[4][2], al[4][2];
        #pragma unroll
        for (int i = 0; i < 4; ++i)
            #pragma unroll
            for (int ks = 0; ks < 2; ++ks) {
                int mt = w * 4 + i;
                ah[i][ks] = *(short8*)&sAh[((mt * 2 + ks) * 64 + ln) * 8];
                al[i][ks] = *(short8*)&sAl[((mt * 2 + ks) * 64 + ln) * 8];
            }
        if (step == 0) {   // old-h at this lane's C positions, once
            #pragma unroll
            for (int v = 0; v < 4; ++v) {
                int ksp = v >> 1;
                int lq2 = (v & 1) * 2 + (lm >> 3);
                int jp = lm & 7;
                #pragma unroll
                for (int i = 0; i < 4; ++i) {
                    int mt = w * 4 + i;
                    #pragma unroll
                    for (int r = 0; r < 4; ++r) {
                        int idx = ((mt * 2 + ksp) * 64 + lq2 * 16 + lq * 4 + r) * 8 + jp;
                        float hi = __uint_as_float((unsigned)sAh[idx] << 16);
                        float lo = __uint_as_float((unsigned)sAl[idx] << 16);
                        hreg[v][i][r] = hi + lo;
                    }
                }
            }
        }
        __syncthreads();   // all reads done before any epilogue write

        #pragma unroll 1
        for (int v = 0; v < 4; ++v) {
            f32x4 C[4][4];  // [gate g][m-tile i]
            #pragma unroll
            for (int g = 0; g < 4; ++g) {
                float bv = sbias[g * 64 + v * 16 + lm];
                #pragma unroll
                for (int i = 0; i < 4; ++i) C[g][i] = (f32x4){bv, bv, bv, bv};
            }
            #pragma unroll
            for (int g = 0; g < 4; ++g) {
                int u = g * 4 + v;
                #pragma unroll
                for (int ks = 0; ks < 2; ++ks) {
                    size_t wb = (size_t)(u * 2 + ks) * 1024 + ln * 8;
                    short8 bh = *(const short8*)&wtg[wb];
                    short8 bl = *(const short8*)&wtg[wb + 512];
                    #pragma unroll
                    for (int i = 0; i < 4; ++i) {
                        C[g][i] = __builtin_amdgcn_mfma_f32_16x16x32_bf16(ah[i][ks], bh, C[g][i], 0, 0, 0);
                        C[g][i] = __builtin_amdgcn_mfma_f32_16x16x32_bf16(ah[i][ks], bl, C[g][i], 0, 0, 0);
                        C[g][i] = __builtin_amdgcn_mfma_f32_16x16x32_bf16(al[i][ks], bh, C[g][i], 0, 0, 0);
                    }
                }
            }
            // epilogue: r/z/n, h' update; write back
            int ksp = v >> 1;
            int lq2 = (v & 1) * 2 + (lm >> 3);
            int jp = lm & 7;
            #pragma unroll
            for (int i = 0; i < 4; ++i) {
                int mt = w * 4 + i;
                #pragma unroll
                for (int r = 0; r < 4; ++r) {
                    float rr = fast_sig(C[0][i][r]);
                    float zz = fast_sig(C[1][i][r]);
                    float nn = fast_tanh(C[2][i][r] + rr * C[3][i][r]);
                    float hnew = (1.0f - zz) * nn + zz * hreg[v][i][r];
                    hreg[v][i][r] = hnew;
                    if (step < 2) {
                        short hi, lo; split_bf16(hnew, hi, lo);
                        int idx = ((mt * 2 + ksp) * 64 + lq2 * 16 + lq * 4 + r) * 8 + jp;
                        sAh[idx] = (unsigned short)hi;
                        sAl[idx] = (unsigned short)lo;
                    } else {
                        buf[(nbase + mt * 16 + lq * 4 + r) * 64 + v * 16 + lm] = hnew;
                    }
                }
            }
        }
        if (step < 2) __syncthreads();
    }
}

// -------- Set2Set (3 steps) + final MLP; 16 graphs per block --------
__global__ __launch_bounds__(256) void k_s2s(
    const float* __restrict__ out,    // [N,64]
    const int*   __restrict__ starts, // [B+1]
    const float* __restrict__ wih,    // [256,128]
    const float* __restrict__ whh,    // [256,64]
    const float* __restrict__ bih,    // [256]
    const float* __restrict__ bhh,    // [256]
    const float* __restrict__ fc1w,   // [128,64]
    const float* __restrict__ fc1b,   // [64]
    const float* __restrict__ fc2w,   // [64]
    const float* __restrict__ fc2b,   // [1]
    float* __restrict__ y)            // [B]
{
    __shared__ float hl[16][64], cl[16][64], qs[16][128];
    __shared__ float gates[16][256];
    __shared__ float ebuf[16][256];
    const int tid = threadIdx.x;
    const int wave = tid >> 6, lane = tid & 63;
    const int g0 = blockIdx.x * 16;

    for (int v = tid; v < 16 * 64; v += 256) { hl[v >> 6][v & 63] = 0.0f; cl[v >> 6][v & 63] = 0.0f; }
    for (int v = tid; v < 16 * 128; v += 256) qs[v >> 7][v & 127] = 0.0f;
    __syncthreads();

    #pragma unroll 1
    for (int step = 0; step < 3; ++step) {
        float acc[16];
        float bsum = bih[tid] + bhh[tid];
        #pragma unroll
        for (int g = 0; g < 16; ++g) acc[g] = bsum;
        for (int k = 0; k < 128; ++k) {
            float w = wih[tid * 128 + k];
            #pragma unroll
            for (int g = 0; g < 16; ++g) acc[g] += w * qs[g][k];
        }
        for (int k = 0; k < 64; ++k) {
            float w = whh[tid * 64 + k];
            #pragma unroll
            for (int g = 0; g < 16; ++g) acc[g] += w * hl[g][k];
        }
        #pragma unroll
        for (int g = 0; g < 16; ++g) gates[g][tid] = acc[g];
        __syncthreads();

        #pragma unroll
        for (int rr = 0; rr < 4; ++rr) {
            int item = rr * 256 + tid;
            int g = item >> 6, l = item & 63;
            float ig = fast_sig(gates[g][l]);
            float fg = fast_sig(gates[g][64 + l]);
            float gg = fast_tanh(gates[g][128 + l]);
            float og = fast_sig(gates[g][192 + l]);
            float cn = fg * cl[g][l] + ig * gg;
            cl[g][l] = cn;
            float hn = og * fast_tanh(cn);
            hl[g][l] = hn;
            qs[g][l] = hn;
        }
        __syncthreads();

        for (int gi = 0; gi < 4; ++gi) {
            int g = wave * 4 + gi;
            int s = starts[g0 + g], e = starts[g0 + g + 1];
            int L = e - s; if (L > 256) L = 256;
            float m = -1e30f;
            for (int c = 0; c * 64 < L; ++c) {
                int j = c * 64 + lane;
                if (j < L) {
                    const float* orow = out + (size_t)(s + j) * 64;
                    float a = 0.0f;
                    #pragma unroll
                    for (int l = 0; l < 64; ++l) a += orow[l] * hl[g][l];
                    ebuf[g][j] = a;
                    m = fmaxf(m, a);
                }
            }
            #pragma unroll
            for (int off = 32; off; off >>= 1) m = fmaxf(m, __shfl_xor(m, off));
            float ds = 0.0f;
            for (int c = 0; c * 64 < L; ++c) {
                int j = c * 64 + lane;
                if (j < L) {
                    float ex = __expf(ebuf[g][j] - m);
                    ebuf[g][j] = ex;
                    ds += ex;
                }
            }
            #pragma unroll
            for (int off = 32; off; off >>= 1) ds += __shfl_xor(ds, off);
            float r = 0.0f;
            for (int j = 0; j < L; ++j)
                r += ebuf[g][j] * out[(size_t)(s + j) * 64 + lane];
            r = (L > 0) ? (r / ds) : 0.0f;
            qs[g][64 + lane] = r;
        }
        __syncthreads();
    }

    #pragma unroll
    for (int rr = 0; rr < 4; ++rr) {
        int item = rr * 256 + tid;
        int g = item >> 6, l = item & 63;
        float a = fc1b[l];
        for (int k = 0; k < 128; ++k) a += qs[g][k] * fc1w[k * 64 + l];
        ebuf[g][l] = fmaxf(a, 0.0f);
    }
    __syncthreads();
    if (tid < 16) {
        float a = fc2b[0];
        #pragma unroll
        for (int l = 0; l < 64; ++l) a += ebuf[tid][l] * fc2w[l];
        y[g0 + tid] = a;
    }
}

extern "C" void kernel_launch(void* const* d_in, const int* in_sizes, int n_in,
                              void* d_out, int out_size, void* d_ws, size_t ws_size,
                              hipStream_t stream) {
    const float* x     = (const float*)d_in[0];
    const float* ea    = (const float*)d_in[1];
    const int*   eidx  = (const int*)d_in[2];
    const int*   batch = (const int*)d_in[3];
    const float* we1   = (const float*)d_in[4];
    const float* be1   = (const float*)d_in[5];
    const float* we2   = (const float*)d_in[6];
    const float* be2   = (const float*)d_in[7];
    const float* root  = (const float*)d_in[8];
    const float* cb    = (const float*)d_in[9];
    const float* gwih  = (const float*)d_in[10];
    const float* gwhh  = (const float*)d_in[11];
    const float* gbih  = (const float*)d_in[12];
    const float* gbhh  = (const float*)d_in[13];
    const float* lwih  = (const float*)d_in[14];
    const float* lwhh  = (const float*)d_in[15];
    const float* lbih  = (const float*)d_in[16];
    const float* lbhh  = (const float*)d_in[17];
    const float* fc1w  = (const float*)d_in[18];
    const float* fc1b  = (const float*)d_in[19];
    const float* fc2w  = (const float*)d_in[20];
    const float* fc2b  = (const float*)d_in[21];

    float* buf = (float*)d_ws;                      // [N,64] msum -> h
    float* cnt = buf + (size_t)N_NODES * 64;        // [N]
    int* starts = (int*)(cnt + N_NODES);            // [B+1]
    size_t off = ((size_t)N_NODES * 64 + N_NODES + N_B + 1) * 4;
    off = (off + 15) & ~(size_t)15;
    unsigned short* wt  = (unsigned short*)((char*)d_ws + off);  // 512KB we2 frags
    unsigned short* wtg = wt + 262144;                            // 64KB GRU frags
    float* gbias = (float*)(wtg + 32768);                         // 256 floats
    float* y = (float*)d_out;

    hipMemsetAsync(d_ws, 0, ((size_t)N_NODES * 64 + N_NODES) * sizeof(float), stream);
    k_prep_w<<<64, 256, 0, stream>>>(we2, wt);
    k_prep_gru<<<8, 256, 0, stream>>>(gwih, gwhh, gbih, gbhh, wtg, gbias);
    k_starts<<<(N_B + 1 + 255) / 256, 256, 0, stream>>>(batch, starts);
    k_edge<<<N_EDGES / 128, 256, 0, stream>>>(x, ea, eidx, we1, be1, wt, be2, buf, cnt);
    k_gru2<<<N_NODES / 256, 256, 0, stream>>>(buf, cnt, x, root, cb, wtg, gbias);
    k_s2s<<<N_B / 16, 256, 0, stream>>>(buf, starts, lwih, lwhh, lbih, lbhh,
                                        fc1w, fc1b, fc2w, fc2b, y);
}